// Round 20
// baseline (317.714 us; speedup 1.0000x reference)
//
#include <hip/hip_runtime.h>
#include <hip/hip_fp16.h>

#define BB   8
#define CC   64
#define HH   128
#define WW   128
#define OCC  128
#define HWx  (HH*WW)
#define KTOT 576
#define SST  584    // ushort row stride: 576 + 8 (1168 B, 16B-multiple)

typedef __attribute__((ext_vector_type(8))) short short8t;
typedef __attribute__((ext_vector_type(8))) _Float16 half8t;
typedef __attribute__((ext_vector_type(4))) float f32x4;

static __device__ __forceinline__ ushort f2h(float f) {
    __half h = __float2half_rn(f);
    return __half_as_ushort(h);
}

// ---- K0: conv_w -> MFMA-fragment-ordered fp16 table -----------------------
__global__ __launch_bounds__(256) void kprep(const float* __restrict__ w,
                                             ushort* __restrict__ wf) {
    int i = blockIdx.x * 256 + threadIdx.x;   // 73728
    int e  = i & 7;
    int t  = i >> 3;
    int l  = t & 63;
    int t2 = t >> 6;                          // wv*18 + ks
    int lr = l & 15, lg = l >> 4;
    int oc = (t2 / 18) * 16 + lr;
    int kg = (t2 % 18) * 32 + lg * 8 + e;
    int c = kg & 63, tap = kg >> 6;
    wf[i] = f2h(w[oc * 576 + c * 9 + tap]);
}

// ---- K0c: off_w [ch][c*9+tap] -> wT [(c*9+tap)*18 + ch] fp32 --------------
__global__ __launch_bounds__(256) void kprepw(const float* __restrict__ ow,
                                              float* __restrict__ wT) {
    int i = blockIdx.x * 256 + threadIdx.x;   // 18*576 = 10368
    if (i < 18 * KTOT) {
        int ch = i / KTOT, r = i - ch * KTOT;
        wT[r * 18 + ch] = ow[i];
    }
}

// ---- K1: offset conv (fp32 exact) FUSED with x->xT fp16 transpose ---------
// grid = BB*HH = 1024, b = bi&7. g = tid>>7 channel half (wave-uniform).
// g=0 waves also emit xT[b][i*WW+j][c] from the center tap they already load.
// FMA order identical to koff5 -> offsets bit-identical.
__global__ __launch_bounds__(256) void koff9(const float* __restrict__ x,
                                             const float* __restrict__ wT,
                                             const float* __restrict__ off_b,
                                             float* __restrict__ offsT,
                                             ushort* __restrict__ xT) {
    int tid = threadIdx.x;
    int b = blockIdx.x & 7;
    int i = blockIdx.x >> 3;
    int g9 = __builtin_amdgcn_readfirstlane((tid >> 7) * 9);  // 0 or 9
    int j = tid & 127;
    const float* xb = x + (size_t)b * CC * HWx;
    ushort* xTrow = xT + ((size_t)b * HWx + i * WW + j) * 64;

    float acc[9];
#pragma unroll
    for (int u = 0; u < 9; ++u) acc[u] = off_b[g9 + u];

    for (int c8 = 0; c8 < CC; c8 += 8) {
        short8t v;
#pragma unroll
        for (int u = 0; u < 8; ++u) {
            int c = c8 + u;
            const float* xc = xb + (size_t)c * HWx;
            float ctr = 0.f;
#pragma unroll
            for (int di = 0; di < 3; ++di) {
                int r = i + di - 1;
                bool rv = (r >= 0) && (r < HH);
#pragma unroll
                for (int dj = 0; dj < 3; ++dj) {
                    int s = j + dj - 1;
                    float xv = (rv && s >= 0 && s < WW) ? xc[r * WW + s] : 0.f;
                    if (di == 1 && dj == 1) ctr = xv;
                    const float* wrow = &wT[(c * 9 + di * 3 + dj) * 18 + g9];
#pragma unroll
                    for (int uu = 0; uu < 9; ++uu)
                        acc[uu] = fmaf(xv, wrow[uu], acc[uu]);
                }
            }
            v[u] = (short)f2h(ctr);
        }
        if (g9 == 0)                      // wave-uniform branch
            *(short8t*)(xTrow + c8) = v;
    }

    float* ob = offsT + ((size_t)(b * HWx) + i * WW + j) * 18 + g9;
#pragma unroll
    for (int u = 0; u < 9; ++u) ob[u] = acc[u];
}

// ---- K2: fused gather + MFMA; line-shared grain + frag weights (R18) -------
// Block: 512 thr, 32 pixels x 128 oc. grid = 4096, b = bi&7 (XCD<->batch).
__global__ __launch_bounds__(512, 4) void kmain20(const ushort* __restrict__ xT,
                                                  const float* __restrict__ offsT,
                                                  const ushort* __restrict__ wf,
                                                  const float* __restrict__ conv_b,
                                                  float* __restrict__ out) {
    __shared__ __align__(16) ushort S[32 * SST];   // 37376 B
    int tid = threadIdx.x;                 // 0..511
    int bi  = blockIdx.x;
    int b   = bi & 7;                      // XCD-affine batch
    int rem = bi >> 3;                     // 0..511
    int oi  = rem >> 2;
    int oj0 = (rem & 3) * 32;

    const ushort* xTb  = xT + (size_t)b * HWx * 64;
    const float*  offb = offsT + (size_t)b * HWx * 18;

    int wv = tid >> 6;                     // wave 0..7: oc tile [16wv,16wv+16)
    int l  = tid & 63;
    int lr = l & 15;
    int lg = l >> 4;
    const ushort* wr0 = wf + ((size_t)(wv * 18) * 64 + l) * 8;

    // ---- phase 1: 2304 subtasks = (pix, tap, 8-ch), 4.5/thread ----
#pragma unroll
    for (int it = 0; it < 5; ++it) {
        int s = tid + it * 512;
        if (s >= 2304) break;
        int pix = s / 72;
        int r   = s - pix * 72;
        int tap = r >> 3;
        int cg  = r & 7;
        int kr = tap / 3, kc = tap - kr * 3;
        int si = oi + ((kr == 0) ? -1 : 0);
        int sj = oj0 + pix + ((kc == 0) ? -1 : 0);
        ushort* Sd = &S[pix * SST + tap * 64 + cg * 8];

        if (si < 0 || sj < 0) {
            uint4 z = {0, 0, 0, 0};
            *(uint4*)Sd = z;
            continue;
        }
        int n    = ((kr == 0) ? 2 : kr - 1) * 3 + ((kc == 0) ? 2 : kc - 1);
        int pidx = si * WW + sj;
        float ox = offb[pidx * 18 + n];
        float oy = offb[pidx * 18 + 9 + n];
        float px = (float)si + ox;
        float py = (float)sj + oy;
        float fx = floorf(px), fy = floorf(py);
        float pxc   = fminf(fmaxf(px, 0.f), 127.f);
        float pyc   = fminf(fmaxf(py, 0.f), 127.f);
        float qltxf = fminf(fmaxf(fx, 0.f), 127.f);
        float qltyf = fminf(fmaxf(fy, 0.f), 127.f);
        float qrbxf = fminf(fmaxf(fx + 1.f, 0.f), 127.f);
        float qrbyf = fminf(fmaxf(fy + 1.f, 0.f), 127.f);
        int qltx = (int)qltxf, qlty = (int)qltyf;
        int qrbx = (int)qrbxf, qrby = (int)qrbyf;
        float glt = (1.f + (qltxf - pxc)) * (1.f + (qltyf - pyc));
        float grb = (1.f - (qrbxf - pxc)) * (1.f - (qrbyf - pyc));
        float glb = (1.f + (qltxf - pxc)) * (1.f - (qrbyf - pyc));
        float grt = (1.f - (qrbxf - pxc)) * (1.f + (qltyf - pyc));
        __half2 hlt = __float2half2_rn(glt);
        __half2 hrb = __float2half2_rn(grb);
        __half2 hlb = __float2half2_rn(glb);
        __half2 hrt = __float2half2_rn(grt);
        int co = cg * 8;
        uint4 lt = *(const uint4*)(xTb + (size_t)(qltx * WW + qlty) * 64 + co);
        uint4 rb = *(const uint4*)(xTb + (size_t)(qrbx * WW + qrby) * 64 + co);
        uint4 lb = *(const uint4*)(xTb + (size_t)(qltx * WW + qrby) * 64 + co);
        uint4 rt = *(const uint4*)(xTb + (size_t)(qrbx * WW + qlty) * 64 + co);
        uint4 o;
        {
            __half2 a;
            a = __hmul2(hlt, __builtin_bit_cast(__half2, lt.x));
            a = __hfma2(hrb, __builtin_bit_cast(__half2, rb.x), a);
            a = __hfma2(hlb, __builtin_bit_cast(__half2, lb.x), a);
            a = __hfma2(hrt, __builtin_bit_cast(__half2, rt.x), a);
            o.x = __builtin_bit_cast(uint, a);
            a = __hmul2(hlt, __builtin_bit_cast(__half2, lt.y));
            a = __hfma2(hrb, __builtin_bit_cast(__half2, rb.y), a);
            a = __hfma2(hlb, __builtin_bit_cast(__half2, lb.y), a);
            a = __hfma2(hrt, __builtin_bit_cast(__half2, rt.y), a);
            o.y = __builtin_bit_cast(uint, a);
            a = __hmul2(hlt, __builtin_bit_cast(__half2, lt.z));
            a = __hfma2(hrb, __builtin_bit_cast(__half2, rb.z), a);
            a = __hfma2(hlb, __builtin_bit_cast(__half2, lb.z), a);
            a = __hfma2(hrt, __builtin_bit_cast(__half2, rt.z), a);
            o.z = __builtin_bit_cast(uint, a);
            a = __hmul2(hlt, __builtin_bit_cast(__half2, lt.w));
            a = __hfma2(hrb, __builtin_bit_cast(__half2, rb.w), a);
            a = __hfma2(hlb, __builtin_bit_cast(__half2, lb.w), a);
            a = __hfma2(hrt, __builtin_bit_cast(__half2, rt.w), a);
            o.w = __builtin_bit_cast(uint, a);
        }
        *(uint4*)Sd = o;
    }
    __syncthreads();

    // ---- phase 2: 128oc x 32pix x 576K GEMM (16x16x32 fp16 MFMA) ----
    f32x4 acc[2];
#pragma unroll
    for (int e = 0; e < 4; ++e) {
        float bv = conv_b[16 * wv + lg * 4 + e];
        acc[0][e] = bv;
        acc[1][e] = bv;
    }
    const ushort* s0 = &S[(lr) * SST + lg * 8];
    const ushort* s1 = &S[(16 + lr) * SST + lg * 8];

#pragma unroll
    for (int ks = 0; ks < 18; ++ks) {
        int kk = ks * 32;
        half8t a0 = *(const half8t*)(wr0 + ks * 512);
        half8t b0 = *(const half8t*)(s0 + kk);
        half8t b1 = *(const half8t*)(s1 + kk);
        acc[0] = __builtin_amdgcn_mfma_f32_16x16x32_f16(a0, b0, acc[0], 0, 0, 0);
        acc[1] = __builtin_amdgcn_mfma_f32_16x16x32_f16(a0, b1, acc[1], 0, 0, 0);
    }

    float* ob = out + ((size_t)b * OCC * HH + oi) * WW + oj0;
#pragma unroll
    for (int p = 0; p < 2; ++p) {
#pragma unroll
        for (int e = 0; e < 4; ++e) {
            int oc  = 16 * wv + lg * 4 + e;
            int col = 16 * p + lr;
            ob[(size_t)oc * HWx + col] = acc[p][e];
        }
    }
}

extern "C" void kernel_launch(void* const* d_in, const int* in_sizes, int n_in,
                              void* d_out, int out_size, void* d_ws, size_t ws_size,
                              hipStream_t stream) {
    const float* x      = (const float*)d_in[0];
    const float* off_w  = (const float*)d_in[1];
    const float* off_b  = (const float*)d_in[2];
    const float* conv_w = (const float*)d_in[3];
    const float* conv_b = (const float*)d_in[4];
    float* out = (float*)d_out;

    ushort* wbf   = (ushort*)d_ws;                              // 147456 B
    float*  offsT = (float*)((char*)d_ws + 147456);             // 9.44 MB
    ushort* xT    = (ushort*)((char*)d_ws + 147456 + 9437184);  // 16.78 MB
    float*  wT    = (float*)((char*)d_ws + 147456 + 9437184 + 16777216); // 41.5 KB

    kprep<<<(OCC * KTOT) / 256, 256, 0, stream>>>(conv_w, wbf);
    kprepw<<<41, 256, 0, stream>>>(off_w, wT);
    koff9<<<BB * HH, 256, 0, stream>>>(x, wT, off_b, offsT, xT);
    kmain20<<<BB * HH * 4, 512, 0, stream>>>(xT, offsT, wbf, conv_b, out);
}

// Round 21
// 121.195 us; speedup vs baseline: 2.6215x; 2.6215x over previous
//
#include <hip/hip_runtime.h>
#include <hip/hip_fp16.h>

#define BB   8
#define CC   64
#define HH   128
#define WW   128
#define OCC  128
#define HWx  (HH*WW)
#define KTOT 576
#define SST  584    // ushort row stride: 576 + 8 (1168 B, 16B-multiple)

typedef __attribute__((ext_vector_type(8))) short short8t;
typedef __attribute__((ext_vector_type(8))) _Float16 half8t;
typedef __attribute__((ext_vector_type(4))) float f32x4;

static __device__ __forceinline__ ushort f2h(float f) {
    __half h = __float2half_rn(f);
    return __half_as_ushort(h);
}

// ---- K0: conv_w -> MFMA-fragment-ordered fp16 table -----------------------
__global__ __launch_bounds__(256) void kprep(const float* __restrict__ w,
                                             ushort* __restrict__ wf) {
    int i = blockIdx.x * 256 + threadIdx.x;   // 73728
    int e  = i & 7;
    int t  = i >> 3;
    int l  = t & 63;
    int t2 = t >> 6;                          // wv*18 + ks
    int lr = l & 15, lg = l >> 4;
    int oc = (t2 / 18) * 16 + lr;
    int kg = (t2 % 18) * 32 + lg * 8 + e;
    int c = kg & 63, tap = kg >> 6;
    wf[i] = f2h(w[oc * 576 + c * 9 + tap]);
}

// ---- K0c: off_w [ch][c*9+tap] -> wT [(c*9+tap)*18 + ch] fp32 --------------
__global__ __launch_bounds__(256) void kprepw(const float* __restrict__ ow,
                                              float* __restrict__ wT) {
    int i = blockIdx.x * 256 + threadIdx.x;   // 18*576 = 10368
    if (i < 18 * KTOT) {
        int ch = i / KTOT, r = i - ch * KTOT;
        wT[r * 18 + ch] = ow[i];
    }
}

// ---- K0b: x NCHW fp32 -> xT NHWC fp16, direct (R18 verbatim) --------------
__global__ __launch_bounds__(256) void ktrans(const float* __restrict__ x,
                                              ushort* __restrict__ xT) {
    int tid = threadIdx.x;
    int b   = blockIdx.x >> 8;
    int p   = (blockIdx.x & 255) * 64 + (tid & 63);
    int cg  = tid >> 6;                  // 0..3 -> channels cg*16..+15
    const float* xb = x + (size_t)b * CC * HWx + p;
    ushort* ob = xT + ((size_t)b * HWx + p) * 64 + cg * 16;
    short8t v0, v1;
#pragma unroll
    for (int e = 0; e < 8; ++e) v0[e] = (short)f2h(xb[(size_t)(cg * 16 + e) * HWx]);
#pragma unroll
    for (int e = 0; e < 8; ++e) v1[e] = (short)f2h(xb[(size_t)(cg * 16 + 8 + e) * HWx]);
    *(short8t*)ob = v0;
    *(short8t*)(ob + 8) = v1;
}

// ---- K1: offset conv (ch 0..17), fp32 exact, LDS-free (R18 verbatim) ------
__global__ __launch_bounds__(256) void koff5(const float* __restrict__ x,
                                             const float* __restrict__ wT,
                                             const float* __restrict__ off_b,
                                             float* __restrict__ offsT) {
    int tid = threadIdx.x;
    int b = blockIdx.x & 7;
    int i = blockIdx.x >> 3;
    int g9 = __builtin_amdgcn_readfirstlane((tid >> 7) * 9);  // wave-uniform
    int j = tid & 127;
    const float* xb = x + (size_t)b * CC * HWx;

    float acc[9];
#pragma unroll
    for (int u = 0; u < 9; ++u) acc[u] = off_b[g9 + u];

    for (int c = 0; c < CC; ++c) {
        const float* xc = xb + (size_t)c * HWx;
#pragma unroll
        for (int di = 0; di < 3; ++di) {
            int r = i + di - 1;
            bool rv = (r >= 0) && (r < HH);
#pragma unroll
            for (int dj = 0; dj < 3; ++dj) {
                int s = j + dj - 1;
                float xv = (rv && s >= 0 && s < WW) ? xc[r * WW + s] : 0.f;
                const float* wrow = &wT[(c * 9 + di * 3 + dj) * 18 + g9];
#pragma unroll
                for (int u = 0; u < 9; ++u)
                    acc[u] = fmaf(xv, wrow[u], acc[u]);
            }
        }
    }
    float* ob = offsT + ((size_t)(b * HWx) + i * WW + j) * 18 + g9;
#pragma unroll
    for (int u = 0; u < 9; ++u) ob[u] = acc[u];
}

static __device__ __forceinline__ __half2 lerp_w(uint ltw, uint rbw, uint lbw, uint rtw,
                                                 __half2 hlt, __half2 hrb,
                                                 __half2 hlb, __half2 hrt) {
    __half2 a;
    a = __hmul2(hlt, __builtin_bit_cast(__half2, ltw));
    a = __hfma2(hrb, __builtin_bit_cast(__half2, rbw), a);
    a = __hfma2(hlb, __builtin_bit_cast(__half2, lbw), a);
    a = __hfma2(hrt, __builtin_bit_cast(__half2, rtw), a);
    return a;
}
static __device__ __forceinline__ uint4 lerp_u4(uint4 lt, uint4 rb, uint4 lb, uint4 rt,
                                                __half2 hlt, __half2 hrb,
                                                __half2 hlb, __half2 hrt) {
    uint4 o;
    o.x = __builtin_bit_cast(uint, lerp_w(lt.x, rb.x, lb.x, rt.x, hlt, hrb, hlb, hrt));
    o.y = __builtin_bit_cast(uint, lerp_w(lt.y, rb.y, lb.y, rt.y, hlt, hrb, hlb, hrt));
    o.z = __builtin_bit_cast(uint, lerp_w(lt.z, rb.z, lb.z, rt.z, hlt, hrb, hlb, hrt));
    o.w = __builtin_bit_cast(uint, lerp_w(lt.w, rb.w, lb.w, rt.w, hlt, hrb, hlb, hrt));
    return o;
}

// ---- K2: fused gather + MFMA; 16-ch grain + frag weights -------------------
// Block: 512 thr, 32 pixels x 128 oc. grid = 4096, b = bi&7 (XCD<->batch).
// Subtask = (pix, tap, 16ch): 1152 subtasks, 2.25/thread. 4 lanes share one
// sample row (one 128B line) -> line-shared; decode cost halved vs 8-ch.
__global__ __launch_bounds__(512, 4) void kmain21(const ushort* __restrict__ xT,
                                                  const float* __restrict__ offsT,
                                                  const ushort* __restrict__ wf,
                                                  const float* __restrict__ conv_b,
                                                  float* __restrict__ out) {
    __shared__ __align__(16) ushort S[32 * SST];   // 37376 B
    int tid = threadIdx.x;                 // 0..511
    int bi  = blockIdx.x;
    int b   = bi & 7;                      // XCD-affine batch
    int rem = bi >> 3;                     // 0..511
    int oi  = rem >> 2;
    int oj0 = (rem & 3) * 32;

    const ushort* xTb  = xT + (size_t)b * HWx * 64;
    const float*  offb = offsT + (size_t)b * HWx * 18;

    int wv = tid >> 6;                     // wave 0..7: oc tile [16wv,16wv+16)
    int l  = tid & 63;
    int lr = l & 15;
    int lg = l >> 4;
    const ushort* wr0 = wf + ((size_t)(wv * 18) * 64 + l) * 8;

    // ---- phase 1: 1152 subtasks = (pix, tap, 16-ch), 2.25/thread ----
#pragma unroll
    for (int it = 0; it < 3; ++it) {
        int s = tid + it * 512;
        if (s >= 1152) break;
        int pix = s / 36;
        int rr  = s - pix * 36;
        int tap = rr >> 2;
        int cg2 = rr & 3;                  // 16-ch group
        int kr = tap / 3, kc = tap - kr * 3;
        int si = oi + ((kr == 0) ? -1 : 0);
        int sj = oj0 + pix + ((kc == 0) ? -1 : 0);
        ushort* Sd = &S[pix * SST + tap * 64 + cg2 * 16];

        if (si < 0 || sj < 0) {
            uint4 z = {0, 0, 0, 0};
            *(uint4*)Sd = z;
            *(uint4*)(Sd + 8) = z;
            continue;
        }
        int n    = ((kr == 0) ? 2 : kr - 1) * 3 + ((kc == 0) ? 2 : kc - 1);
        int pidx = si * WW + sj;
        float ox = offb[pidx * 18 + n];
        float oy = offb[pidx * 18 + 9 + n];
        float px = (float)si + ox;
        float py = (float)sj + oy;
        float fx = floorf(px), fy = floorf(py);
        float pxc   = fminf(fmaxf(px, 0.f), 127.f);
        float pyc   = fminf(fmaxf(py, 0.f), 127.f);
        float qltxf = fminf(fmaxf(fx, 0.f), 127.f);
        float qltyf = fminf(fmaxf(fy, 0.f), 127.f);
        float qrbxf = fminf(fmaxf(fx + 1.f, 0.f), 127.f);
        float qrbyf = fminf(fmaxf(fy + 1.f, 0.f), 127.f);
        int qltx = (int)qltxf, qlty = (int)qltyf;
        int qrbx = (int)qrbxf, qrby = (int)qrbyf;
        int co = cg2 * 16;
        const ushort* plt = xTb + (size_t)(qltx * WW + qlty) * 64 + co;
        const ushort* prb = xTb + (size_t)(qrbx * WW + qrby) * 64 + co;
        const ushort* plb = xTb + (size_t)(qltx * WW + qrby) * 64 + co;
        const ushort* prt = xTb + (size_t)(qrbx * WW + qlty) * 64 + co;
        uint4 lt0 = *(const uint4*)(plt);  uint4 lt1 = *(const uint4*)(plt + 8);
        uint4 rb0 = *(const uint4*)(prb);  uint4 rb1 = *(const uint4*)(prb + 8);
        uint4 lb0 = *(const uint4*)(plb);  uint4 lb1 = *(const uint4*)(plb + 8);
        uint4 rt0 = *(const uint4*)(prt);  uint4 rt1 = *(const uint4*)(prt + 8);

        float glt = (1.f + (qltxf - pxc)) * (1.f + (qltyf - pyc));
        float grb = (1.f - (qrbxf - pxc)) * (1.f - (qrbyf - pyc));
        float glb = (1.f + (qltxf - pxc)) * (1.f - (qrbyf - pyc));
        float grt = (1.f - (qrbxf - pxc)) * (1.f + (qltyf - pyc));
        __half2 hlt = __float2half2_rn(glt);
        __half2 hrb = __float2half2_rn(grb);
        __half2 hlb = __float2half2_rn(glb);
        __half2 hrt = __float2half2_rn(grt);

        uint4 o0 = lerp_u4(lt0, rb0, lb0, rt0, hlt, hrb, hlb, hrt);
        uint4 o1 = lerp_u4(lt1, rb1, lb1, rt1, hlt, hrb, hlb, hrt);
        *(uint4*)(Sd)     = o0;
        *(uint4*)(Sd + 8) = o1;
    }
    __syncthreads();

    // ---- phase 2: 128oc x 32pix x 576K GEMM (16x16x32 fp16 MFMA) ----
    f32x4 acc[2];
#pragma unroll
    for (int e = 0; e < 4; ++e) {
        float bv = conv_b[16 * wv + lg * 4 + e];
        acc[0][e] = bv;
        acc[1][e] = bv;
    }
    const ushort* s0 = &S[(lr) * SST + lg * 8];
    const ushort* s1 = &S[(16 + lr) * SST + lg * 8];

#pragma unroll
    for (int ks = 0; ks < 18; ++ks) {
        int kk = ks * 32;
        half8t a0 = *(const half8t*)(wr0 + ks * 512);
        half8t b0 = *(const half8t*)(s0 + kk);
        half8t b1 = *(const half8t*)(s1 + kk);
        acc[0] = __builtin_amdgcn_mfma_f32_16x16x32_f16(a0, b0, acc[0], 0, 0, 0);
        acc[1] = __builtin_amdgcn_mfma_f32_16x16x32_f16(a0, b1, acc[1], 0, 0, 0);
    }

    float* ob = out + ((size_t)b * OCC * HH + oi) * WW + oj0;
#pragma unroll
    for (int p = 0; p < 2; ++p) {
#pragma unroll
        for (int e = 0; e < 4; ++e) {
            int oc  = 16 * wv + lg * 4 + e;
            int col = 16 * p + lr;
            ob[(size_t)oc * HWx + col] = acc[p][e];
        }
    }
}

extern "C" void kernel_launch(void* const* d_in, const int* in_sizes, int n_in,
                              void* d_out, int out_size, void* d_ws, size_t ws_size,
                              hipStream_t stream) {
    const float* x      = (const float*)d_in[0];
    const float* off_w  = (const float*)d_in[1];
    const float* off_b  = (const float*)d_in[2];
    const float* conv_w = (const float*)d_in[3];
    const float* conv_b = (const float*)d_in[4];
    float* out = (float*)d_out;

    ushort* wbf   = (ushort*)d_ws;                              // 147456 B
    float*  offsT = (float*)((char*)d_ws + 147456);             // 9.44 MB
    ushort* xT    = (ushort*)((char*)d_ws + 147456 + 9437184);  // 16.78 MB
    float*  wT    = (float*)((char*)d_ws + 147456 + 9437184 + 16777216); // 41.5 KB

    kprep<<<(OCC * KTOT) / 256, 256, 0, stream>>>(conv_w, wbf);
    kprepw<<<41, 256, 0, stream>>>(off_w, wT);
    ktrans<<<BB * (HWx / 64), 256, 0, stream>>>(x, xT);
    koff5<<<BB * HH, 256, 0, stream>>>(x, wT, off_b, offsT);
    kmain21<<<BB * HH * 4, 512, 0, stream>>>(xT, offsT, wbf, conv_b, out);
}

// Round 22
// 109.574 us; speedup vs baseline: 2.8995x; 1.1061x over previous
//
#include <hip/hip_runtime.h>
#include <hip/hip_fp16.h>

#define BB   8
#define CC   64
#define HH   128
#define WW   128
#define OCC  128
#define HWx  (HH*WW)
#define KTOT 576
#define SST  584    // ushort row stride: 576 + 8 (1168 B, 16B-multiple)

typedef __attribute__((ext_vector_type(8))) short short8t;
typedef __attribute__((ext_vector_type(8))) _Float16 half8t;
typedef __attribute__((ext_vector_type(4))) float f32x4;

static __device__ __forceinline__ ushort f2h(float f) {
    __half h = __float2half_rn(f);
    return __half_as_ushort(h);
}

// ---- K0c: off_w [ch][c*9+tap] -> wT [(c*9+tap)*18 + ch] fp32 --------------
__global__ __launch_bounds__(256) void kprepw(const float* __restrict__ ow,
                                              float* __restrict__ wT) {
    int i = blockIdx.x * 256 + threadIdx.x;   // 18*576 = 10368
    if (i < 18 * KTOT) {
        int ch = i / KTOT, r = i - ch * KTOT;
        wT[r * 18 + ch] = ow[i];
    }
}

// ---- KFRONT: koff5 (blocks 0..1023) + ktrans (1024..3071) + kprep (3072..3359)
// Role bodies byte-identical to R21's koff5 / ktrans / kprep.
// koff occupies 4 blk/CU (VGPR 20, no LDS, 8 possible) -> ktrans/kprep blocks
// co-reside in the slack, absorbing their runtime into koff's stall time.
__global__ __launch_bounds__(256) void kfront(const float* __restrict__ x,
                                              const float* __restrict__ wT,
                                              const float* __restrict__ off_b,
                                              float* __restrict__ offsT,
                                              ushort* __restrict__ xT,
                                              const float* __restrict__ cw,
                                              ushort* __restrict__ wf) {
    int bi  = blockIdx.x;
    int tid = threadIdx.x;

    if (bi < 1024) {
        // ---------------- role: offset conv (fp32 exact, LDS-free) ----------
        int b = bi & 7;
        int i = bi >> 3;
        int g9 = __builtin_amdgcn_readfirstlane((tid >> 7) * 9);  // wave-uniform
        int j = tid & 127;
        const float* xb = x + (size_t)b * CC * HWx;

        float acc[9];
#pragma unroll
        for (int u = 0; u < 9; ++u) acc[u] = off_b[g9 + u];

        for (int c = 0; c < CC; ++c) {
            const float* xc = xb + (size_t)c * HWx;
#pragma unroll
            for (int di = 0; di < 3; ++di) {
                int r = i + di - 1;
                bool rv = (r >= 0) && (r < HH);
#pragma unroll
                for (int dj = 0; dj < 3; ++dj) {
                    int s = j + dj - 1;
                    float xv = (rv && s >= 0 && s < WW) ? xc[r * WW + s] : 0.f;
                    const float* wrow = &wT[(c * 9 + di * 3 + dj) * 18 + g9];
#pragma unroll
                    for (int u = 0; u < 9; ++u)
                        acc[u] = fmaf(xv, wrow[u], acc[u]);
                }
            }
        }
        float* ob = offsT + ((size_t)(b * HWx) + i * WW + j) * 18 + g9;
#pragma unroll
        for (int u = 0; u < 9; ++u) ob[u] = acc[u];

    } else if (bi < 3072) {
        // ---------------- role: x NCHW fp32 -> xT NHWC fp16 -----------------
        int bb = bi - 1024;
        int b  = bb >> 8;
        int p  = (bb & 255) * 64 + (tid & 63);
        int cg = tid >> 6;                  // 0..3 -> channels cg*16..+15
        const float* xb = x + (size_t)b * CC * HWx + p;
        ushort* ob = xT + ((size_t)b * HWx + p) * 64 + cg * 16;
        short8t v0, v1;
#pragma unroll
        for (int e = 0; e < 8; ++e) v0[e] = (short)f2h(xb[(size_t)(cg * 16 + e) * HWx]);
#pragma unroll
        for (int e = 0; e < 8; ++e) v1[e] = (short)f2h(xb[(size_t)(cg * 16 + 8 + e) * HWx]);
        *(short8t*)ob = v0;
        *(short8t*)(ob + 8) = v1;

    } else {
        // ---------------- role: conv_w -> fragment-ordered fp16 table -------
        int i = (bi - 3072) * 256 + tid;    // 0..73727
        int e  = i & 7;
        int t  = i >> 3;
        int l  = t & 63;
        int t2 = t >> 6;                    // wv*18 + ks
        int lr = l & 15, lg = l >> 4;
        int oc = (t2 / 18) * 16 + lr;
        int kg = (t2 % 18) * 32 + lg * 8 + e;
        int c = kg & 63, tap = kg >> 6;
        wf[i] = f2h(cw[oc * 576 + c * 9 + tap]);
    }
}

static __device__ __forceinline__ __half2 lerp_w(uint ltw, uint rbw, uint lbw, uint rtw,
                                                 __half2 hlt, __half2 hrb,
                                                 __half2 hlb, __half2 hrt) {
    __half2 a;
    a = __hmul2(hlt, __builtin_bit_cast(__half2, ltw));
    a = __hfma2(hrb, __builtin_bit_cast(__half2, rbw), a);
    a = __hfma2(hlb, __builtin_bit_cast(__half2, lbw), a);
    a = __hfma2(hrt, __builtin_bit_cast(__half2, rtw), a);
    return a;
}
static __device__ __forceinline__ uint4 lerp_u4(uint4 lt, uint4 rb, uint4 lb, uint4 rt,
                                                __half2 hlt, __half2 hrb,
                                                __half2 hlb, __half2 hrt) {
    uint4 o;
    o.x = __builtin_bit_cast(uint, lerp_w(lt.x, rb.x, lb.x, rt.x, hlt, hrb, hlb, hrt));
    o.y = __builtin_bit_cast(uint, lerp_w(lt.y, rb.y, lb.y, rt.y, hlt, hrb, hlb, hrt));
    o.z = __builtin_bit_cast(uint, lerp_w(lt.z, rb.z, lb.z, rt.z, hlt, hrb, hlb, hrt));
    o.w = __builtin_bit_cast(uint, lerp_w(lt.w, rb.w, lb.w, rt.w, hlt, hrb, hlb, hrt));
    return o;
}

// ---- K2: fused gather + MFMA; 16-ch grain + frag weights (R21 verbatim) ----
__global__ __launch_bounds__(512, 4) void kmain22(const ushort* __restrict__ xT,
                                                  const float* __restrict__ offsT,
                                                  const ushort* __restrict__ wf,
                                                  const float* __restrict__ conv_b,
                                                  float* __restrict__ out) {
    __shared__ __align__(16) ushort S[32 * SST];   // 37376 B
    int tid = threadIdx.x;                 // 0..511
    int bi  = blockIdx.x;
    int b   = bi & 7;                      // XCD-affine batch
    int rem = bi >> 3;                     // 0..511
    int oi  = rem >> 2;
    int oj0 = (rem & 3) * 32;

    const ushort* xTb  = xT + (size_t)b * HWx * 64;
    const float*  offb = offsT + (size_t)b * HWx * 18;

    int wv = tid >> 6;                     // wave 0..7: oc tile [16wv,16wv+16)
    int l  = tid & 63;
    int lr = l & 15;
    int lg = l >> 4;
    const ushort* wr0 = wf + ((size_t)(wv * 18) * 64 + l) * 8;

    // ---- phase 1: 1152 subtasks = (pix, tap, 16-ch), 2.25/thread ----
#pragma unroll
    for (int it = 0; it < 3; ++it) {
        int s = tid + it * 512;
        if (s >= 1152) break;
        int pix = s / 36;
        int rr  = s - pix * 36;
        int tap = rr >> 2;
        int cg2 = rr & 3;                  // 16-ch group
        int kr = tap / 3, kc = tap - kr * 3;
        int si = oi + ((kr == 0) ? -1 : 0);
        int sj = oj0 + pix + ((kc == 0) ? -1 : 0);
        ushort* Sd = &S[pix * SST + tap * 64 + cg2 * 16];

        if (si < 0 || sj < 0) {
            uint4 z = {0, 0, 0, 0};
            *(uint4*)Sd = z;
            *(uint4*)(Sd + 8) = z;
            continue;
        }
        int n    = ((kr == 0) ? 2 : kr - 1) * 3 + ((kc == 0) ? 2 : kc - 1);
        int pidx = si * WW + sj;
        float ox = offb[pidx * 18 + n];
        float oy = offb[pidx * 18 + 9 + n];
        float px = (float)si + ox;
        float py = (float)sj + oy;
        float fx = floorf(px), fy = floorf(py);
        float pxc   = fminf(fmaxf(px, 0.f), 127.f);
        float pyc   = fminf(fmaxf(py, 0.f), 127.f);
        float qltxf = fminf(fmaxf(fx, 0.f), 127.f);
        float qltyf = fminf(fmaxf(fy, 0.f), 127.f);
        float qrbxf = fminf(fmaxf(fx + 1.f, 0.f), 127.f);
        float qrbyf = fminf(fmaxf(fy + 1.f, 0.f), 127.f);
        int qltx = (int)qltxf, qlty = (int)qltyf;
        int qrbx = (int)qrbxf, qrby = (int)qrbyf;
        int co = cg2 * 16;
        const ushort* plt = xTb + (size_t)(qltx * WW + qlty) * 64 + co;
        const ushort* prb = xTb + (size_t)(qrbx * WW + qrby) * 64 + co;
        const ushort* plb = xTb + (size_t)(qltx * WW + qrby) * 64 + co;
        const ushort* prt = xTb + (size_t)(qrbx * WW + qlty) * 64 + co;
        uint4 lt0 = *(const uint4*)(plt);  uint4 lt1 = *(const uint4*)(plt + 8);
        uint4 rb0 = *(const uint4*)(prb);  uint4 rb1 = *(const uint4*)(prb + 8);
        uint4 lb0 = *(const uint4*)(plb);  uint4 lb1 = *(const uint4*)(plb + 8);
        uint4 rt0 = *(const uint4*)(prt);  uint4 rt1 = *(const uint4*)(prt + 8);

        float glt = (1.f + (qltxf - pxc)) * (1.f + (qltyf - pyc));
        float grb = (1.f - (qrbxf - pxc)) * (1.f - (qrbyf - pyc));
        float glb = (1.f + (qltxf - pxc)) * (1.f - (qrbyf - pyc));
        float grt = (1.f - (qrbxf - pxc)) * (1.f + (qltyf - pyc));
        __half2 hlt = __float2half2_rn(glt);
        __half2 hrb = __float2half2_rn(grb);
        __half2 hlb = __float2half2_rn(glb);
        __half2 hrt = __float2half2_rn(grt);

        uint4 o0 = lerp_u4(lt0, rb0, lb0, rt0, hlt, hrb, hlb, hrt);
        uint4 o1 = lerp_u4(lt1, rb1, lb1, rt1, hlt, hrb, hlb, hrt);
        *(uint4*)(Sd)     = o0;
        *(uint4*)(Sd + 8) = o1;
    }
    __syncthreads();

    // ---- phase 2: 128oc x 32pix x 576K GEMM (16x16x32 fp16 MFMA) ----
    f32x4 acc[2];
#pragma unroll
    for (int e = 0; e < 4; ++e) {
        float bv = conv_b[16 * wv + lg * 4 + e];
        acc[0][e] = bv;
        acc[1][e] = bv;
    }
    const ushort* s0 = &S[(lr) * SST + lg * 8];
    const ushort* s1 = &S[(16 + lr) * SST + lg * 8];

#pragma unroll
    for (int ks = 0; ks < 18; ++ks) {
        int kk = ks * 32;
        half8t a0 = *(const half8t*)(wr0 + ks * 512);
        half8t b0 = *(const half8t*)(s0 + kk);
        half8t b1 = *(const half8t*)(s1 + kk);
        acc[0] = __builtin_amdgcn_mfma_f32_16x16x32_f16(a0, b0, acc[0], 0, 0, 0);
        acc[1] = __builtin_amdgcn_mfma_f32_16x16x32_f16(a0, b1, acc[1], 0, 0, 0);
    }

    float* ob = out + ((size_t)b * OCC * HH + oi) * WW + oj0;
#pragma unroll
    for (int p = 0; p < 2; ++p) {
#pragma unroll
        for (int e = 0; e < 4; ++e) {
            int oc  = 16 * wv + lg * 4 + e;
            int col = 16 * p + lr;
            ob[(size_t)oc * HWx + col] = acc[p][e];
        }
    }
}

extern "C" void kernel_launch(void* const* d_in, const int* in_sizes, int n_in,
                              void* d_out, int out_size, void* d_ws, size_t ws_size,
                              hipStream_t stream) {
    const float* x      = (const float*)d_in[0];
    const float* off_w  = (const float*)d_in[1];
    const float* off_b  = (const float*)d_in[2];
    const float* conv_w = (const float*)d_in[3];
    const float* conv_b = (const float*)d_in[4];
    float* out = (float*)d_out;

    ushort* wbf   = (ushort*)d_ws;                              // 147456 B
    float*  offsT = (float*)((char*)d_ws + 147456);             // 9.44 MB
    ushort* xT    = (ushort*)((char*)d_ws + 147456 + 9437184);  // 16.78 MB
    float*  wT    = (float*)((char*)d_ws + 147456 + 9437184 + 16777216); // 41.5 KB

    kprepw<<<41, 256, 0, stream>>>(off_w, wT);
    kfront<<<3360, 256, 0, stream>>>(x, wT, off_b, offsT, xT, conv_w, wbf);
    kmain22<<<BB * HH * 4, 512, 0, stream>>>(xT, offsT, wbf, conv_b, out);
}